// Round 13
// baseline (63.114 us; speedup 1.0000x reference)
//
#include <hip/hip_runtime.h>
#include <hip/hip_bf16.h>
#include <stdint.h>

#define L_SEQ 2048
#define D_MODEL 1024
#define NH 16
#define DH 64
#define NEG_INF -1e9f

typedef short bf16x4 __attribute__((ext_vector_type(4)));
typedef short bf16x8 __attribute__((ext_vector_type(8)));
typedef float f32x4 __attribute__((ext_vector_type(4)));
typedef unsigned short ushort_t;
typedef const __attribute__((address_space(1))) void* gas_t;
typedef __attribute__((address_space(3))) void* las_t;

#define MFMA16(a, b, c) __builtin_amdgcn_mfma_f32_16x16x32_bf16((a), (b), (c), 0, 0, 0)

__device__ __forceinline__ ushort_t f2b(float f) {
  union { float f; unsigned u; } v; v.f = f;
  unsigned r = v.u + 0x7fffu + ((v.u >> 16) & 1u);
  return (ushort_t)(r >> 16);
}

// ---------------- f32 -> bf16 conversion of x + 4 weights ----------------
__global__ __launch_bounds__(256) void cvt_kernel(
    const float* __restrict__ x, const float* __restrict__ wq,
    const float* __restrict__ wk, const float* __restrict__ wv,
    const float* __restrict__ wo, ushort_t* __restrict__ out) {
  long e = ((long)blockIdx.x * 256 + threadIdx.x) * 4;
  const float* src; long off;
  if (e < 2097152L)      { src = x;  off = e; }
  else if (e < 3145728L) { src = wq; off = e - 2097152L; }
  else if (e < 4194304L) { src = wk; off = e - 3145728L; }
  else if (e < 5242880L) { src = wv; off = e - 4194304L; }
  else                   { src = wo; off = e - 5242880L; }
  float4 v = *(const float4*)(src + off);
  ushort4 o;
  o.x = f2b(v.x); o.y = f2b(v.y); o.z = f2b(v.z); o.w = f2b(v.w);
  *(ushort4*)(out + e) = o;
}

// ---------------- QKV GEMM: 128x128, ring-4 DISTANCE-3 counted-vmcnt + T2 swizzle ---
// Stage issued AFTER the barrier: at barrier(s) all waves finished compute(s-1),
// so writing buffer (s+3)&3 == (s-1)&3 is race-free. Loads for step s issued at
// s-3 -> 3 iterations of latency cover (was 2).
__global__ __launch_bounds__(512, 4) void gemm_qkv(
    const ushort_t* __restrict__ A, const ushort_t* __restrict__ Wbase,
    const float* __restrict__ b0, const float* __restrict__ b1,
    const float* __restrict__ b2, ushort_t* __restrict__ outbase) {
  const int z = blockIdx.z;
  const ushort_t* W = Wbase + (long)z * (D_MODEL * D_MODEL);
  const float* bias = (z == 0) ? b0 : ((z == 1) ? b1 : b2);
  const float scale = (z == 0) ? 0.125f : 1.0f;

  __shared__ ushort_t As[4 * 128 * 32];
  __shared__ ushort_t Bs[4 * 128 * 32];
  const int tid = threadIdx.x;
  const int lane = tid & 63;
  const int wid = tid >> 6;
  const int wm = wid >> 2, wn = wid & 3;
  const int m0 = blockIdx.x * 128, n0 = blockIdx.y * 128;
  const int K = D_MODEL;
  const int l15 = lane & 15;
  const int lgc = lane >> 4;
  const int xs = (l15 >> 1) & 3;

  const int soff = tid * 16;
  const int srow = soff >> 6;
  const int schunk = (soff >> 4) & 3;
  const int swzcol = ((schunk ^ ((srow >> 1) & 3)) << 3);

  const ushort_t* Aptr = A + (long)(m0 + srow) * K + swzcol;
  const ushort_t* Wptr = W + (long)(n0 + srow) * K + swzcol;

  auto stage = [&](int buf, int step) {
    __builtin_amdgcn_global_load_lds(
        (gas_t)(const void*)(Aptr + step * 32),
        (las_t)(void*)((char*)As + buf * 8192 + soff), 16, 0, 0);
    __builtin_amdgcn_global_load_lds(
        (gas_t)(const void*)(Wptr + step * 32),
        (las_t)(void*)((char*)Bs + buf * 8192 + soff), 16, 0, 0);
  };

  f32x4 acc[4][2] = {};

  auto compute = [&](int buf) {
    const ushort_t* Ab = As + buf * (128 * 32);
    const ushort_t* Bb = Bs + buf * (128 * 32);
    bf16x8 af[4], bf[2];
#pragma unroll
    for (int t = 0; t < 4; ++t)
      af[t] = *(const bf16x8*)(Ab + (wm * 64 + t * 16 + l15) * 32 +
                               ((lgc ^ xs) << 3));
#pragma unroll
    for (int t = 0; t < 2; ++t)
      bf[t] = *(const bf16x8*)(Bb + (wn * 32 + t * 16 + l15) * 32 +
                               ((lgc ^ xs) << 3));
#pragma unroll
    for (int mt = 0; mt < 4; ++mt)
#pragma unroll
      for (int nt = 0; nt < 2; ++nt)
        acc[mt][nt] = MFMA16(af[mt], bf[nt], acc[mt][nt]);
  };

  const int NSTEP = K / 32;  // 32
  stage(0, 0);
  stage(1, 1);
  stage(2, 2);
  for (int s = 0; s < NSTEP - 3; ++s) {
    // outstanding here: stages s+1, s+2 (4 loads) -> stage s landed
    asm volatile("s_waitcnt vmcnt(4)" ::: "memory");
    __builtin_amdgcn_s_barrier();
    __builtin_amdgcn_sched_barrier(0);
    stage((s + 3) & 3, s + 3);
    compute(s & 3);
  }
  asm volatile("s_waitcnt vmcnt(4)" ::: "memory");
  __builtin_amdgcn_s_barrier();
  __builtin_amdgcn_sched_barrier(0);
  compute((NSTEP - 3) & 3);
  asm volatile("s_waitcnt vmcnt(2)" ::: "memory");
  __builtin_amdgcn_s_barrier();
  __builtin_amdgcn_sched_barrier(0);
  compute((NSTEP - 2) & 3);
  asm volatile("s_waitcnt vmcnt(0)" ::: "memory");
  __builtin_amdgcn_s_barrier();
  __builtin_amdgcn_sched_barrier(0);
  compute((NSTEP - 1) & 3);

  const int lg4 = (lane >> 4) * 4;
  ushort_t* o = outbase + (long)z * ((long)NH * L_SEQ * DH);
#pragma unroll
  for (int mt = 0; mt < 4; ++mt)
#pragma unroll
    for (int nt = 0; nt < 2; ++nt)
#pragma unroll
      for (int r = 0; r < 4; ++r) {
        int row = m0 + wm * 64 + mt * 16 + lg4 + r;
        int col = n0 + wn * 32 + nt * 16 + l15;
        float v = (acc[mt][nt][r] + bias[col]) * scale;
        o[((long)(col >> 6) * L_SEQ + row) * DH + (col & 63)] = f2b(v);
      }
}

// ---------------- out-proj GEMM: 128x64, ring-4 DISTANCE-3 + T2 swizzle ------------
__global__ __launch_bounds__(256, 3) void gemm_out(
    const ushort_t* __restrict__ A, const ushort_t* __restrict__ W,
    const float* __restrict__ bias, float* __restrict__ o) {
  __shared__ ushort_t As[4 * 128 * 32];
  __shared__ ushort_t Bs[4 * 64 * 32];
  const int tid = threadIdx.x;
  const int lane = tid & 63;
  const int wid = tid >> 6;
  const int wm = wid >> 1, wn = wid & 1;
  const int m0 = blockIdx.x * 128, n0 = blockIdx.y * 64;
  const int K = D_MODEL;
  const int l15 = lane & 15;
  const int lgc = lane >> 4;
  const int xs = (l15 >> 1) & 3;

  const int soff = tid * 16;
  const int srow = soff >> 6;
  const int schunk = (soff >> 4) & 3;
  const int swzcol = ((schunk ^ ((srow >> 1) & 3)) << 3);

  const ushort_t* Aptr0 = A + (long)(m0 + srow) * K + swzcol;
  const ushort_t* Aptr1 = A + (long)(m0 + 64 + srow) * K + swzcol;
  const ushort_t* Wptr  = W + (long)(n0 + srow) * K + swzcol;

  auto stage = [&](int buf, int step) {
    __builtin_amdgcn_global_load_lds(
        (gas_t)(const void*)(Aptr0 + step * 32),
        (las_t)(void*)((char*)As + buf * 8192 + soff), 16, 0, 0);
    __builtin_amdgcn_global_load_lds(
        (gas_t)(const void*)(Aptr1 + step * 32),
        (las_t)(void*)((char*)As + buf * 8192 + 4096 + soff), 16, 0, 0);
    __builtin_amdgcn_global_load_lds(
        (gas_t)(const void*)(Wptr + step * 32),
        (las_t)(void*)((char*)Bs + buf * 4096 + soff), 16, 0, 0);
  };

  f32x4 acc[4][2] = {};

  auto compute = [&](int buf) {
    const ushort_t* Ab = As + buf * (128 * 32);
    const ushort_t* Bb = Bs + buf * (64 * 32);
    bf16x8 af[4], bf[2];
#pragma unroll
    for (int t = 0; t < 4; ++t)
      af[t] = *(const bf16x8*)(Ab + (wm * 64 + t * 16 + l15) * 32 +
                               ((lgc ^ xs) << 3));
#pragma unroll
    for (int t = 0; t < 2; ++t)
      bf[t] = *(const bf16x8*)(Bb + (wn * 32 + t * 16 + l15) * 32 +
                               ((lgc ^ xs) << 3));
#pragma unroll
    for (int mt = 0; mt < 4; ++mt)
#pragma unroll
      for (int nt = 0; nt < 2; ++nt)
        acc[mt][nt] = MFMA16(af[mt], bf[nt], acc[mt][nt]);
  };

  const int NSTEP = K / 32;  // 32
  stage(0, 0);
  stage(1, 1);
  stage(2, 2);
  for (int s = 0; s < NSTEP - 3; ++s) {
    // outstanding here: stages s+1, s+2 (6 loads) -> stage s landed
    asm volatile("s_waitcnt vmcnt(6)" ::: "memory");
    __builtin_amdgcn_s_barrier();
    __builtin_amdgcn_sched_barrier(0);
    stage((s + 3) & 3, s + 3);
    compute(s & 3);
  }
  asm volatile("s_waitcnt vmcnt(6)" ::: "memory");
  __builtin_amdgcn_s_barrier();
  __builtin_amdgcn_sched_barrier(0);
  compute((NSTEP - 3) & 3);
  asm volatile("s_waitcnt vmcnt(3)" ::: "memory");
  __builtin_amdgcn_s_barrier();
  __builtin_amdgcn_sched_barrier(0);
  compute((NSTEP - 2) & 3);
  asm volatile("s_waitcnt vmcnt(0)" ::: "memory");
  __builtin_amdgcn_s_barrier();
  __builtin_amdgcn_sched_barrier(0);
  compute((NSTEP - 1) & 3);

  const int lg4 = (lane >> 4) * 4;
#pragma unroll
  for (int mt = 0; mt < 4; ++mt)
#pragma unroll
    for (int nt = 0; nt < 2; ++nt)
#pragma unroll
      for (int r = 0; r < 4; ++r) {
        int row = m0 + wm * 64 + mt * 16 + lg4 + r;
        int col = n0 + wn * 32 + nt * 16 + l15;
        o[(long)row * D_MODEL + col] = acc[mt][nt][r] + bias[col];
      }
}

// ---------------- fused local+global attention (R12, frozen) ----------------
#define VTW 228
__global__ __launch_bounds__(512) void attn_fused(
    const ushort_t* __restrict__ QKV, const int* __restrict__ gidx, int NG,
    ushort_t* __restrict__ attn_out) {
  __shared__ ushort_t smem[28800];  // 57600 B

  const int tid = threadIdx.x;
  const int lane = tid & 63;
  const int w = tid >> 6;            // 0..7
  const int h = blockIdx.y;
  const int q0 = blockIdx.x * 128;

  const long hoff = (long)h * L_SEQ * DH;
  const ushort_t* Qh = QKV + hoff;
  const ushort_t* Kh = QKV + (long)NH * L_SEQ * DH + hoff;
  const ushort_t* Vh = QKV + 2L * NH * L_SEQ * DH + hoff;

  const int l15 = lane & 15, lg = lane >> 4;
  const int ql = q0 + w * 16 + l15;

  ushort_t* kl = smem;               // 192 x 72
  ushort_t* kg = smem + 192 * 72;    // 208 x 72
  ushort_t* vtl = smem;              // 64 x 196 (V phase)
  ushort_t* vtg = smem + 64 * 196;   // 64 x 228

  int4 vstL[3];
#pragma unroll
  for (int it = 0; it < 3; ++it) {
    int c = tid + it * 512;
    int r = c >> 3, cc = (c & 7) * 8;
    int sr = q0 - 32 + r;
    sr = sr < 0 ? 0 : (sr > L_SEQ - 1 ? L_SEQ - 1 : sr);
    vstL[it] = *(const int4*)(Vh + (long)sr * DH + cc);
  }
  int4 vstG[4];
#pragma unroll
  for (int it = 0; it < 4; ++it) {
    int c = tid + it * 512;
    int cl = c < 1664 ? c : 1663;
    int r = cl >> 3, cc = (cl & 7) * 8;
    int idx = r < NG ? r : NG - 1;
    vstG[it] = *(const int4*)(Vh + (long)gidx[idx] * DH + cc);
  }
  bf16x8 qf0 = *(const bf16x8*)(Qh + (long)ql * DH + lg * 8);
  bf16x8 qf1 = *(const bf16x8*)(Qh + (long)ql * DH + 32 + lg * 8);

#pragma unroll
  for (int it = 0; it < 3; ++it) {
    int c = tid + it * 512;
    int r = c >> 3, cc = (c & 7) * 8;
    int sr = q0 - 32 + r;
    sr = sr < 0 ? 0 : (sr > L_SEQ - 1 ? L_SEQ - 1 : sr);
    int4 v = *(const int4*)(Kh + (long)sr * DH + cc);
    *(int4*)(kl + r * 72 + cc) = v;
  }
#pragma unroll
  for (int it = 0; it < 4; ++it) {
    int c = tid + it * 512;
    if (c < 1664) {
      int r = c >> 3, cc = (c & 7) * 8;
      int idx = r < NG ? r : NG - 1;
      int4 v = *(const int4*)(Kh + (long)gidx[idx] * DH + cc);
      *(int4*)(kg + r * 72 + cc) = v;
    }
  }
  __syncthreads();

  f32x4 sl[5];
#pragma unroll
  for (int kt = 0; kt < 5; ++kt) {
    f32x4 c = {};
    const ushort_t* kr = kl + (w * 16 + kt * 16 + l15) * 72;
    bf16x8 k0 = *(const bf16x8*)(kr + lg * 8);
    bf16x8 k1 = *(const bf16x8*)(kr + 32 + lg * 8);
    c = MFMA16(k0, qf0, c);
    c = MFMA16(k1, qf1, c);
    sl[kt] = c;
  }
  f32x4 sg[13];
#pragma unroll
  for (int kt = 0; kt < 13; ++kt) {
    f32x4 c = {};
    bf16x8 k0 = *(const bf16x8*)(kg + (kt * 16 + l15) * 72 + lg * 8);
    bf16x8 k1 = *(const bf16x8*)(kg + (kt * 16 + l15) * 72 + 32 + lg * 8);
    c = MFMA16(k0, qf0, c);
    c = MFMA16(k1, qf1, c);
    sg[kt] = c;
  }
  __syncthreads();  // K buffers dead; smem becomes VT

#pragma unroll
  for (int it = 0; it < 3; ++it) {
    int c = tid + it * 512;
    int r = c >> 3, cc = (c & 7) * 8;
    ushort_t tmp[8]; *(int4*)tmp = vstL[it];
#pragma unroll
    for (int j = 0; j < 8; ++j) vtl[(cc + j) * 196 + r] = tmp[j];
  }
#pragma unroll
  for (int it = 0; it < 4; ++it) {
    int c = tid + it * 512;
    if (c < 1664) {
      int r = c >> 3, cc = (c & 7) * 8;
      ushort_t tmp[8]; *(int4*)tmp = vstG[it];
#pragma unroll
      for (int j = 0; j < 8; ++j) vtg[(cc + j) * VTW + r] = tmp[j];
    }
  }
  for (int i = tid; i < 64 * 20; i += 512)
    vtg[(i / 20) * VTW + 208 + (i % 20)] = 0;

  float mx = NEG_INF;
#pragma unroll
  for (int kt = 0; kt < 5; ++kt)
#pragma unroll
    for (int r4 = 0; r4 < 4; ++r4) {
      int key = q0 - 32 + w * 16 + kt * 16 + lg * 4 + r4;
      int d = key - ql;
      bool valid = (key >= 0) && (key < L_SEQ) && (d <= 32) && (d >= -32);
      float v = valid ? sl[kt][r4] : NEG_INF;
      sl[kt][r4] = v;
      mx = fmaxf(mx, v);
    }
  mx = fmaxf(mx, __shfl_xor(mx, 16, 64));
  mx = fmaxf(mx, __shfl_xor(mx, 32, 64));
  float den = 0.f;
#pragma unroll
  for (int kt = 0; kt < 5; ++kt)
#pragma unroll
    for (int r4 = 0; r4 < 4; ++r4) {
      float e = __expf(sl[kt][r4] - mx);
      sl[kt][r4] = e;
      den += e;
    }
  den += __shfl_xor(den, 16, 64);
  den += __shfl_xor(den, 32, 64);
  const float psl = 0.7f / den;

  float mg = NEG_INF;
#pragma unroll
  for (int t = 0; t < 13; ++t)
#pragma unroll
    for (int r4 = 0; r4 < 4; ++r4) {
      int i = t * 16 + lg * 4 + r4;
      float v = (i < NG) ? sg[t][r4] : NEG_INF;
      sg[t][r4] = v;
      mg = fmaxf(mg, v);
    }
  mg = fmaxf(mg, __shfl_xor(mg, 16, 64));
  mg = fmaxf(mg, __shfl_xor(mg, 32, 64));
  float deng = 0.f;
#pragma unroll
  for (int t = 0; t < 13; ++t)
#pragma unroll
    for (int r4 = 0; r4 < 4; ++r4) {
      float e = __expf(sg[t][r4] - mg);
      sg[t][r4] = e;
      deng += e;
    }
  deng += __shfl_xor(deng, 16, 64);
  deng += __shfl_xor(deng, 32, 64);
  const float psg = 0.3f / deng;

  bf16x8 pl[3];
#pragma unroll
  for (int s = 0; s < 2; ++s)
#pragma unroll
    for (int j = 0; j < 4; ++j) {
      pl[s][j]     = (short)f2b(sl[2 * s][j] * psl);
      pl[s][j + 4] = (short)f2b(sl[2 * s + 1][j] * psl);
    }
#pragma unroll
  for (int j = 0; j < 4; ++j) {
    pl[2][j]     = (short)f2b(sl[4][j] * psl);
    pl[2][j + 4] = 0;
  }
  bf16x8 pg[7];
#pragma unroll
  for (int s = 0; s < 6; ++s)
#pragma unroll
    for (int j = 0; j < 4; ++j) {
      pg[s][j]     = (short)f2b(sg[2 * s][j] * psg);
      pg[s][j + 4] = (short)f2b(sg[2 * s + 1][j] * psg);
    }
#pragma unroll
  for (int j = 0; j < 4; ++j) {
    pg[6][j]     = (short)f2b(sg[12][j] * psg);
    pg[6][j + 4] = 0;
  }
  __syncthreads();  // VT ready

#pragma unroll
  for (int dt = 0; dt < 4; ++dt) {
    f32x4 c = {};
    const ushort_t* vrowL = vtl + (dt * 16 + l15) * 196 + w * 16 + lg * 4;
#pragma unroll
    for (int s = 0; s < 3; ++s) {
      bf16x4 lo = *(const bf16x4*)(vrowL + s * 32);
      bf16x4 hi = *(const bf16x4*)(vrowL + s * 32 + (s < 2 ? 16 : 0));
      bf16x8 vf = __builtin_shufflevector(lo, hi, 0, 1, 2, 3, 4, 5, 6, 7);
      c = MFMA16(pl[s], vf, c);
    }
    const ushort_t* vrowG = vtg + (dt * 16 + l15) * VTW + lg * 4;
#pragma unroll
    for (int s = 0; s < 7; ++s) {
      bf16x4 lo = *(const bf16x4*)(vrowG + s * 32);
      bf16x4 hi = *(const bf16x4*)(vrowG + s * 32 + 16);
      bf16x8 vf = __builtin_shufflevector(lo, hi, 0, 1, 2, 3, 4, 5, 6, 7);
      c = MFMA16(pg[s], vf, c);
    }
#pragma unroll
    for (int r4 = 0; r4 < 4; ++r4) {
      int row = q0 + w * 16 + lg * 4 + r4;
      attn_out[(long)row * D_MODEL + h * DH + dt * 16 + l15] = f2b(c[r4]);
    }
  }
}

extern "C" void kernel_launch(void* const* d_in, const int* in_sizes, int n_in,
                              void* d_out, int out_size, void* d_ws, size_t ws_size,
                              hipStream_t stream) {
  const float* x  = (const float*)d_in[0];
  const float* Wq = (const float*)d_in[1];
  const float* bq = (const float*)d_in[2];
  const float* Wk = (const float*)d_in[3];
  const float* bk = (const float*)d_in[4];
  const float* Wv = (const float*)d_in[5];
  const float* bv = (const float*)d_in[6];
  const float* Wo = (const float*)d_in[7];
  const float* bo = (const float*)d_in[8];
  const int* gidx = (const int*)d_in[9];
  const int NG = in_sizes[9];

  ushort_t* ws = (ushort_t*)d_ws;
  ushort_t* xb    = ws;                  // x bf16: 2M elems
  ushort_t* wb    = ws + 2097152L;       // 4 weights bf16: 4 x 1M
  ushort_t* qkv   = ws + 6291456L;       // Q,K,V bf16 head-major: 3 x 2M
  ushort_t* attn  = ws + 12582912L;      // attention bf16 [L][D]: 2M

  cvt_kernel<<<6144, 256, 0, stream>>>(x, Wq, Wk, Wv, Wo, ws);
  gemm_qkv<<<dim3(16, 8, 3), 512, 0, stream>>>(xb, wb, bq, bk, bv, qkv);
  attn_fused<<<dim3(16, 16), 512, 0, stream>>>(qkv, gidx, NG, attn);
  gemm_out<<<dim3(16, 16), 256, 0, stream>>>(attn, wb + 3145728L, bo,
                                             (float*)d_out);
}

// Round 14
// 58.104 us; speedup vs baseline: 1.0862x; 1.0862x over previous
//
#include <hip/hip_runtime.h>
#include <hip/hip_bf16.h>
#include <stdint.h>

#define L_SEQ 2048
#define D_MODEL 1024
#define NH 16
#define DH 64
#define NEG_INF -1e9f

typedef short bf16x4 __attribute__((ext_vector_type(4)));
typedef short bf16x8 __attribute__((ext_vector_type(8)));
typedef float f32x4 __attribute__((ext_vector_type(4)));
typedef unsigned short ushort_t;
typedef const __attribute__((address_space(1))) void* gas_t;
typedef __attribute__((address_space(3))) void* las_t;

#define MFMA16(a, b, c) __builtin_amdgcn_mfma_f32_16x16x32_bf16((a), (b), (c), 0, 0, 0)

__device__ __forceinline__ ushort_t f2b(float f) {
  union { float f; unsigned u; } v; v.f = f;
  unsigned r = v.u + 0x7fffu + ((v.u >> 16) & 1u);
  return (ushort_t)(r >> 16);
}

// ---------------- f32 -> bf16 conversion of x + 4 weights ----------------
__global__ __launch_bounds__(256) void cvt_kernel(
    const float* __restrict__ x, const float* __restrict__ wq,
    const float* __restrict__ wk, const float* __restrict__ wv,
    const float* __restrict__ wo, ushort_t* __restrict__ out) {
  long e = ((long)blockIdx.x * 256 + threadIdx.x) * 4;
  const float* src; long off;
  if (e < 2097152L)      { src = x;  off = e; }
  else if (e < 3145728L) { src = wq; off = e - 2097152L; }
  else if (e < 4194304L) { src = wk; off = e - 3145728L; }
  else if (e < 5242880L) { src = wv; off = e - 4194304L; }
  else                   { src = wo; off = e - 5242880L; }
  float4 v = *(const float4*)(src + off);
  ushort4 o;
  o.x = f2b(v.x); o.y = f2b(v.y); o.z = f2b(v.z); o.w = f2b(v.w);
  *(ushort4*)(out + e) = o;
}

// ---------------- QKV GEMM: 128x128, ring-4 counted-vmcnt + T2 swizzle + T1 XCD ----
// 1D grid of 384 blocks. XCD swizzle (384%8==0): lid=(bid&7)*48+(bid>>3).
// Logical order lid = m_tile + 16*n_all -> each XCD's 48 contiguous logical
// blocks share 3 W-panels + the xb panel (L2-resident per XCD).
__global__ __launch_bounds__(512, 4) void gemm_qkv(
    const ushort_t* __restrict__ A, const ushort_t* __restrict__ Wbase,
    const float* __restrict__ b0, const float* __restrict__ b1,
    const float* __restrict__ b2, ushort_t* __restrict__ outbase) {
  const int bid = blockIdx.x;
  const int lid = (bid & 7) * 48 + (bid >> 3);
  const int m_tile = lid & 15;
  const int n_all = lid >> 4;          // 0..23
  const int z = n_all >> 3;
  const int n_tile = n_all & 7;

  const ushort_t* W = Wbase + (long)z * (D_MODEL * D_MODEL);
  const float* bias = (z == 0) ? b0 : ((z == 1) ? b1 : b2);
  const float scale = (z == 0) ? 0.125f : 1.0f;

  __shared__ ushort_t As[4 * 128 * 32];
  __shared__ ushort_t Bs[4 * 128 * 32];
  const int tid = threadIdx.x;
  const int lane = tid & 63;
  const int wid = tid >> 6;
  const int wm = wid >> 2, wn = wid & 3;
  const int m0 = m_tile * 128, n0 = n_tile * 128;
  const int K = D_MODEL;
  const int l15 = lane & 15;
  const int lgc = lane >> 4;
  const int xs = (l15 >> 1) & 3;

  const int soff = tid * 16;
  const int srow = soff >> 6;
  const int schunk = (soff >> 4) & 3;
  const int swzcol = ((schunk ^ ((srow >> 1) & 3)) << 3);

  const ushort_t* Aptr = A + (long)(m0 + srow) * K + swzcol;
  const ushort_t* Wptr = W + (long)(n0 + srow) * K + swzcol;

  auto stage = [&](int buf, int step) {
    __builtin_amdgcn_global_load_lds(
        (gas_t)(const void*)(Aptr + step * 32),
        (las_t)(void*)((char*)As + buf * 8192 + soff), 16, 0, 0);
    __builtin_amdgcn_global_load_lds(
        (gas_t)(const void*)(Wptr + step * 32),
        (las_t)(void*)((char*)Bs + buf * 8192 + soff), 16, 0, 0);
  };

  f32x4 acc[4][2] = {};

  auto compute = [&](int buf) {
    const ushort_t* Ab = As + buf * (128 * 32);
    const ushort_t* Bb = Bs + buf * (128 * 32);
    bf16x8 af[4], bf[2];
#pragma unroll
    for (int t = 0; t < 4; ++t)
      af[t] = *(const bf16x8*)(Ab + (wm * 64 + t * 16 + l15) * 32 +
                               ((lgc ^ xs) << 3));
#pragma unroll
    for (int t = 0; t < 2; ++t)
      bf[t] = *(const bf16x8*)(Bb + (wn * 32 + t * 16 + l15) * 32 +
                               ((lgc ^ xs) << 3));
#pragma unroll
    for (int mt = 0; mt < 4; ++mt)
#pragma unroll
      for (int nt = 0; nt < 2; ++nt)
        acc[mt][nt] = MFMA16(af[mt], bf[nt], acc[mt][nt]);
  };

  const int NSTEP = K / 32;
  stage(0, 0);
  stage(1, 1);
  for (int s = 0; s < NSTEP - 2; ++s) {
    stage((s + 2) & 3, s + 2);
    asm volatile("s_waitcnt vmcnt(4)" ::: "memory");
    __builtin_amdgcn_s_barrier();
    __builtin_amdgcn_sched_barrier(0);
    compute(s & 3);
  }
  asm volatile("s_waitcnt vmcnt(2)" ::: "memory");
  __builtin_amdgcn_s_barrier();
  __builtin_amdgcn_sched_barrier(0);
  compute((NSTEP - 2) & 3);
  asm volatile("s_waitcnt vmcnt(0)" ::: "memory");
  __builtin_amdgcn_s_barrier();
  __builtin_amdgcn_sched_barrier(0);
  compute((NSTEP - 1) & 3);

  const int lg4 = (lane >> 4) * 4;
  ushort_t* o = outbase + (long)z * ((long)NH * L_SEQ * DH);
#pragma unroll
  for (int mt = 0; mt < 4; ++mt)
#pragma unroll
    for (int nt = 0; nt < 2; ++nt)
#pragma unroll
      for (int r = 0; r < 4; ++r) {
        int row = m0 + wm * 64 + mt * 16 + lg4 + r;
        int col = n0 + wn * 32 + nt * 16 + l15;
        float v = (acc[mt][nt][r] + bias[col]) * scale;
        o[((long)(col >> 6) * L_SEQ + row) * DH + (col & 63)] = f2b(v);
      }
}

// ---------------- out-proj GEMM: 128x64, ring-4 + T2 swizzle + T1 XCD ----------------
// 1D grid of 256 blocks; lid=(bid&7)*32+(bid>>3); lid = m_tile + 16*n_tile.
__global__ __launch_bounds__(256, 3) void gemm_out(
    const ushort_t* __restrict__ A, const ushort_t* __restrict__ W,
    const float* __restrict__ bias, float* __restrict__ o) {
  const int bid = blockIdx.x;
  const int lid = (bid & 7) * 32 + (bid >> 3);
  const int m_tile = lid & 15;
  const int n_tile = lid >> 4;         // 0..15

  __shared__ ushort_t As[4 * 128 * 32];
  __shared__ ushort_t Bs[4 * 64 * 32];
  const int tid = threadIdx.x;
  const int lane = tid & 63;
  const int wid = tid >> 6;
  const int wm = wid >> 1, wn = wid & 1;
  const int m0 = m_tile * 128, n0 = n_tile * 64;
  const int K = D_MODEL;
  const int l15 = lane & 15;
  const int lgc = lane >> 4;
  const int xs = (l15 >> 1) & 3;

  const int soff = tid * 16;
  const int srow = soff >> 6;
  const int schunk = (soff >> 4) & 3;
  const int swzcol = ((schunk ^ ((srow >> 1) & 3)) << 3);

  const ushort_t* Aptr0 = A + (long)(m0 + srow) * K + swzcol;
  const ushort_t* Aptr1 = A + (long)(m0 + 64 + srow) * K + swzcol;
  const ushort_t* Wptr  = W + (long)(n0 + srow) * K + swzcol;

  auto stage = [&](int buf, int step) {
    __builtin_amdgcn_global_load_lds(
        (gas_t)(const void*)(Aptr0 + step * 32),
        (las_t)(void*)((char*)As + buf * 8192 + soff), 16, 0, 0);
    __builtin_amdgcn_global_load_lds(
        (gas_t)(const void*)(Aptr1 + step * 32),
        (las_t)(void*)((char*)As + buf * 8192 + 4096 + soff), 16, 0, 0);
    __builtin_amdgcn_global_load_lds(
        (gas_t)(const void*)(Wptr + step * 32),
        (las_t)(void*)((char*)Bs + buf * 4096 + soff), 16, 0, 0);
  };

  f32x4 acc[4][2] = {};

  auto compute = [&](int buf) {
    const ushort_t* Ab = As + buf * (128 * 32);
    const ushort_t* Bb = Bs + buf * (64 * 32);
    bf16x8 af[4], bf[2];
#pragma unroll
    for (int t = 0; t < 4; ++t)
      af[t] = *(const bf16x8*)(Ab + (wm * 64 + t * 16 + l15) * 32 +
                               ((lgc ^ xs) << 3));
#pragma unroll
    for (int t = 0; t < 2; ++t)
      bf[t] = *(const bf16x8*)(Bb + (wn * 32 + t * 16 + l15) * 32 +
                               ((lgc ^ xs) << 3));
#pragma unroll
    for (int mt = 0; mt < 4; ++mt)
#pragma unroll
      for (int nt = 0; nt < 2; ++nt)
        acc[mt][nt] = MFMA16(af[mt], bf[nt], acc[mt][nt]);
  };

  const int NSTEP = K / 32;
  stage(0, 0);
  stage(1, 1);
  for (int s = 0; s < NSTEP - 2; ++s) {
    stage((s + 2) & 3, s + 2);
    asm volatile("s_waitcnt vmcnt(6)" ::: "memory");
    __builtin_amdgcn_s_barrier();
    __builtin_amdgcn_sched_barrier(0);
    compute(s & 3);
  }
  asm volatile("s_waitcnt vmcnt(3)" ::: "memory");
  __builtin_amdgcn_s_barrier();
  __builtin_amdgcn_sched_barrier(0);
  compute((NSTEP - 2) & 3);
  asm volatile("s_waitcnt vmcnt(0)" ::: "memory");
  __builtin_amdgcn_s_barrier();
  __builtin_amdgcn_sched_barrier(0);
  compute((NSTEP - 1) & 3);

  const int lg4 = (lane >> 4) * 4;
#pragma unroll
  for (int mt = 0; mt < 4; ++mt)
#pragma unroll
    for (int nt = 0; nt < 2; ++nt)
#pragma unroll
      for (int r = 0; r < 4; ++r) {
        int row = m0 + wm * 64 + mt * 16 + lg4 + r;
        int col = n0 + wn * 32 + nt * 16 + l15;
        o[(long)row * D_MODEL + col] = acc[mt][nt][r] + bias[col];
      }
}

// ---------------- fused local+global attention (R12, frozen) ----------------
#define VTW 228
__global__ __launch_bounds__(512) void attn_fused(
    const ushort_t* __restrict__ QKV, const int* __restrict__ gidx, int NG,
    ushort_t* __restrict__ attn_out) {
  __shared__ ushort_t smem[28800];  // 57600 B

  const int tid = threadIdx.x;
  const int lane = tid & 63;
  const int w = tid >> 6;            // 0..7
  const int h = blockIdx.y;
  const int q0 = blockIdx.x * 128;

  const long hoff = (long)h * L_SEQ * DH;
  const ushort_t* Qh = QKV + hoff;
  const ushort_t* Kh = QKV + (long)NH * L_SEQ * DH + hoff;
  const ushort_t* Vh = QKV + 2L * NH * L_SEQ * DH + hoff;

  const int l15 = lane & 15, lg = lane >> 4;
  const int ql = q0 + w * 16 + l15;

  ushort_t* kl = smem;               // 192 x 72
  ushort_t* kg = smem + 192 * 72;    // 208 x 72
  ushort_t* vtl = smem;              // 64 x 196 (V phase)
  ushort_t* vtg = smem + 64 * 196;   // 64 x 228

  int4 vstL[3];
#pragma unroll
  for (int it = 0; it < 3; ++it) {
    int c = tid + it * 512;
    int r = c >> 3, cc = (c & 7) * 8;
    int sr = q0 - 32 + r;
    sr = sr < 0 ? 0 : (sr > L_SEQ - 1 ? L_SEQ - 1 : sr);
    vstL[it] = *(const int4*)(Vh + (long)sr * DH + cc);
  }
  int4 vstG[4];
#pragma unroll
  for (int it = 0; it < 4; ++it) {
    int c = tid + it * 512;
    int cl = c < 1664 ? c : 1663;
    int r = cl >> 3, cc = (cl & 7) * 8;
    int idx = r < NG ? r : NG - 1;
    vstG[it] = *(const int4*)(Vh + (long)gidx[idx] * DH + cc);
  }
  bf16x8 qf0 = *(const bf16x8*)(Qh + (long)ql * DH + lg * 8);
  bf16x8 qf1 = *(const bf16x8*)(Qh + (long)ql * DH + 32 + lg * 8);

#pragma unroll
  for (int it = 0; it < 3; ++it) {
    int c = tid + it * 512;
    int r = c >> 3, cc = (c & 7) * 8;
    int sr = q0 - 32 + r;
    sr = sr < 0 ? 0 : (sr > L_SEQ - 1 ? L_SEQ - 1 : sr);
    int4 v = *(const int4*)(Kh + (long)sr * DH + cc);
    *(int4*)(kl + r * 72 + cc) = v;
  }
#pragma unroll
  for (int it = 0; it < 4; ++it) {
    int c = tid + it * 512;
    if (c < 1664) {
      int r = c >> 3, cc = (c & 7) * 8;
      int idx = r < NG ? r : NG - 1;
      int4 v = *(const int4*)(Kh + (long)gidx[idx] * DH + cc);
      *(int4*)(kg + r * 72 + cc) = v;
    }
  }
  __syncthreads();

  f32x4 sl[5];
#pragma unroll
  for (int kt = 0; kt < 5; ++kt) {
    f32x4 c = {};
    const ushort_t* kr = kl + (w * 16 + kt * 16 + l15) * 72;
    bf16x8 k0 = *(const bf16x8*)(kr + lg * 8);
    bf16x8 k1 = *(const bf16x8*)(kr + 32 + lg * 8);
    c = MFMA16(k0, qf0, c);
    c = MFMA16(k1, qf1, c);
    sl[kt] = c;
  }
  f32x4 sg[13];
#pragma unroll
  for (int kt = 0; kt < 13; ++kt) {
    f32x4 c = {};
    bf16x8 k0 = *(const bf16x8*)(kg + (kt * 16 + l15) * 72 + lg * 8);
    bf16x8 k1 = *(const bf16x8*)(kg + (kt * 16 + l15) * 72 + 32 + lg * 8);
    c = MFMA16(k0, qf0, c);
    c = MFMA16(k1, qf1, c);
    sg[kt] = c;
  }
  __syncthreads();  // K buffers dead; smem becomes VT

#pragma unroll
  for (int it = 0; it < 3; ++it) {
    int c = tid + it * 512;
    int r = c >> 3, cc = (c & 7) * 8;
    ushort_t tmp[8]; *(int4*)tmp = vstL[it];
#pragma unroll
    for (int j = 0; j < 8; ++j) vtl[(cc + j) * 196 + r] = tmp[j];
  }
#pragma unroll
  for (int it = 0; it < 4; ++it) {
    int c = tid + it * 512;
    if (c < 1664) {
      int r = c >> 3, cc = (c & 7) * 8;
      ushort_t tmp[8]; *(int4*)tmp = vstG[it];
#pragma unroll
      for (int j = 0; j < 8; ++j) vtg[(cc + j) * VTW + r] = tmp[j];
    }
  }
  for (int i = tid; i < 64 * 20; i += 512)
    vtg[(i / 20) * VTW + 208 + (i % 20)] = 0;

  float mx = NEG_INF;
#pragma unroll
  for (int kt = 0; kt < 5; ++kt)
#pragma unroll
    for (int r4 = 0; r4 < 4; ++r4) {
      int key = q0 - 32 + w * 16 + kt * 16 + lg * 4 + r4;
      int d = key - ql;
      bool valid = (key >= 0) && (key < L_SEQ) && (d <= 32) && (d >= -32);
      float v = valid ? sl[kt][r4] : NEG_INF;
      sl[kt][r4] = v;
      mx = fmaxf(mx, v);
    }
  mx = fmaxf(mx, __shfl_xor(mx, 16, 64));
  mx = fmaxf(mx, __shfl_xor(mx, 32, 64));
  float den = 0.f;
#pragma unroll
  for (int kt = 0; kt < 5; ++kt)
#pragma unroll
    for (int r4 = 0; r4 < 4; ++r4) {
      float e = __expf(sl[kt][r4] - mx);
      sl[kt][r4] = e;
      den += e;
    }
  den += __shfl_xor(den, 16, 64);
  den += __shfl_xor(den, 32, 64);
  const float psl = 0.7f / den;

  float mg = NEG_INF;
#pragma unroll
  for (int t = 0; t < 13; ++t)
#pragma unroll
    for (int r4 = 0; r4 < 4; ++r4) {
      int i = t * 16 + lg * 4 + r4;
      float v = (i < NG) ? sg[t][r4] : NEG_INF;
      sg[t][r4] = v;
      mg = fmaxf(mg, v);
    }
  mg = fmaxf(mg, __shfl_xor(mg, 16, 64));
  mg = fmaxf(mg, __shfl_xor(mg, 32, 64));
  float deng = 0.f;
#pragma unroll
  for (int t = 0; t < 13; ++t)
#pragma unroll
    for (int r4 = 0; r4 < 4; ++r4) {
      float e = __expf(sg[t][r4] - mg);
      sg[t][r4] = e;
      deng += e;
    }
  deng += __shfl_xor(deng, 16, 64);
  deng += __shfl_xor(deng, 32, 64);
  const float psg = 0.3f / deng;

  bf16x8 pl[3];
#pragma unroll
  for (int s = 0; s < 2; ++s)
#pragma unroll
    for (int j = 0; j < 4; ++j) {
      pl[s][j]     = (short)f2b(sl[2 * s][j] * psl);
      pl[s][j + 4] = (short)f2b(sl[2 * s + 1][j] * psl);
    }
#pragma unroll
  for (int j = 0; j < 4; ++j) {
    pl[2][j]     = (short)f2b(sl[4][j] * psl);
    pl[2][j + 4] = 0;
  }
  bf16x8 pg[7];
#pragma unroll
  for (int s = 0; s < 6; ++s)
#pragma unroll
    for (int j = 0; j < 4; ++j) {
      pg[s][j]     = (short)f2b(sg[2 * s][j] * psg);
      pg[s][j + 4] = (short)f2b(sg[2 * s + 1][j] * psg);
    }
#pragma unroll
  for (int j = 0; j < 4; ++j) {
    pg[6][j]     = (short)f2b(sg[12][j] * psg);
    pg[6][j + 4] = 0;
  }
  __syncthreads();  // VT ready

#pragma unroll
  for (int dt = 0; dt < 4; ++dt) {
    f32x4 c = {};
    const ushort_t* vrowL = vtl + (dt * 16 + l15) * 196 + w * 16 + lg * 4;
#pragma unroll
    for (int s = 0; s < 3; ++s) {
      bf16x4 lo = *(const bf16x4*)(vrowL + s * 32);
      bf16x4 hi = *(const bf16x4*)(vrowL + s * 32 + (s < 2 ? 16 : 0));
      bf16x8 vf = __builtin_shufflevector(lo, hi, 0, 1, 2, 3, 4, 5, 6, 7);
      c = MFMA16(pl[s], vf, c);
    }
    const ushort_t* vrowG = vtg + (dt * 16 + l15) * VTW + lg * 4;
#pragma unroll
    for (int s = 0; s < 7; ++s) {
      bf16x4 lo = *(const bf16x4*)(vrowG + s * 32);
      bf16x4 hi = *(const bf16x4*)(vrowG + s * 32 + 16);
      bf16x8 vf = __builtin_shufflevector(lo, hi, 0, 1, 2, 3, 4, 5, 6, 7);
      c = MFMA16(pg[s], vf, c);
    }
#pragma unroll
    for (int r4 = 0; r4 < 4; ++r4) {
      int row = q0 + w * 16 + lg * 4 + r4;
      attn_out[(long)row * D_MODEL + h * DH + dt * 16 + l15] = f2b(c[r4]);
    }
  }
}

extern "C" void kernel_launch(void* const* d_in, const int* in_sizes, int n_in,
                              void* d_out, int out_size, void* d_ws, size_t ws_size,
                              hipStream_t stream) {
  const float* x  = (const float*)d_in[0];
  const float* Wq = (const float*)d_in[1];
  const float* bq = (const float*)d_in[2];
  const float* Wk = (const float*)d_in[3];
  const float* bk = (const float*)d_in[4];
  const float* Wv = (const float*)d_in[5];
  const float* bv = (const float*)d_in[6];
  const float* Wo = (const float*)d_in[7];
  const float* bo = (const float*)d_in[8];
  const int* gidx = (const int*)d_in[9];
  const int NG = in_sizes[9];

  ushort_t* ws = (ushort_t*)d_ws;
  ushort_t* xb    = ws;                  // x bf16: 2M elems
  ushort_t* wb    = ws + 2097152L;       // 4 weights bf16: 4 x 1M
  ushort_t* qkv   = ws + 6291456L;       // Q,K,V bf16 head-major: 3 x 2M
  ushort_t* attn  = ws + 12582912L;      // attention bf16 [L][D]: 2M

  cvt_kernel<<<6144, 256, 0, stream>>>(x, Wq, Wk, Wv, Wo, ws);
  gemm_qkv<<<384, 512, 0, stream>>>(xb, wb, bq, bk, bv, qkv);
  attn_fused<<<dim3(16, 16), 512, 0, stream>>>(qkv, gidx, NG, attn);
  gemm_out<<<256, 256, 0, stream>>>(attn, wb + 3145728L, bo,
                                    (float*)d_out);
}

// Round 15
// 57.702 us; speedup vs baseline: 1.0938x; 1.0070x over previous
//
#include <hip/hip_runtime.h>
#include <hip/hip_bf16.h>
#include <stdint.h>

#define L_SEQ 2048
#define D_MODEL 1024
#define NH 16
#define DH 64
#define NEG_INF -1e9f

typedef short bf16x4 __attribute__((ext_vector_type(4)));
typedef short bf16x8 __attribute__((ext_vector_type(8)));
typedef float f32x4 __attribute__((ext_vector_type(4)));
typedef unsigned short ushort_t;
typedef const __attribute__((address_space(1))) void* gas_t;
typedef __attribute__((address_space(3))) void* las_t;

#define MFMA16(a, b, c) __builtin_amdgcn_mfma_f32_16x16x32_bf16((a), (b), (c), 0, 0, 0)

__device__ __forceinline__ ushort_t f2b(float f) {
  union { float f; unsigned u; } v; v.f = f;
  unsigned r = v.u + 0x7fffu + ((v.u >> 16) & 1u);
  return (ushort_t)(r >> 16);
}

// ---------------- f32 -> bf16 conversion of x + 4 weights ----------------
__global__ __launch_bounds__(256) void cvt_kernel(
    const float* __restrict__ x, const float* __restrict__ wq,
    const float* __restrict__ wk, const float* __restrict__ wv,
    const float* __restrict__ wo, ushort_t* __restrict__ out) {
  long e = ((long)blockIdx.x * 256 + threadIdx.x) * 4;
  const float* src; long off;
  if (e < 2097152L)      { src = x;  off = e; }
  else if (e < 3145728L) { src = wq; off = e - 2097152L; }
  else if (e < 4194304L) { src = wk; off = e - 3145728L; }
  else if (e < 5242880L) { src = wv; off = e - 4194304L; }
  else                   { src = wo; off = e - 5242880L; }
  float4 v = *(const float4*)(src + off);
  ushort4 o;
  o.x = f2b(v.x); o.y = f2b(v.y); o.z = f2b(v.z); o.w = f2b(v.w);
  *(ushort4*)(out + e) = o;
}

// ---------------- QKV GEMM: 128x128, ring-4 counted-vmcnt + T2 + T1 (R14) ----
__global__ __launch_bounds__(512, 4) void gemm_qkv(
    const ushort_t* __restrict__ A, const ushort_t* __restrict__ Wbase,
    const float* __restrict__ b0, const float* __restrict__ b1,
    const float* __restrict__ b2, ushort_t* __restrict__ outbase) {
  const int bid = blockIdx.x;
  const int lid = (bid & 7) * 48 + (bid >> 3);
  const int m_tile = lid & 15;
  const int n_all = lid >> 4;          // 0..23
  const int z = n_all >> 3;
  const int n_tile = n_all & 7;

  const ushort_t* W = Wbase + (long)z * (D_MODEL * D_MODEL);
  const float* bias = (z == 0) ? b0 : ((z == 1) ? b1 : b2);
  const float scale = (z == 0) ? 0.125f : 1.0f;

  __shared__ ushort_t As[4 * 128 * 32];
  __shared__ ushort_t Bs[4 * 128 * 32];
  const int tid = threadIdx.x;
  const int lane = tid & 63;
  const int wid = tid >> 6;
  const int wm = wid >> 2, wn = wid & 3;
  const int m0 = m_tile * 128, n0 = n_tile * 128;
  const int K = D_MODEL;
  const int l15 = lane & 15;
  const int lgc = lane >> 4;
  const int xs = (l15 >> 1) & 3;

  const int soff = tid * 16;
  const int srow = soff >> 6;
  const int schunk = (soff >> 4) & 3;
  const int swzcol = ((schunk ^ ((srow >> 1) & 3)) << 3);

  const ushort_t* Aptr = A + (long)(m0 + srow) * K + swzcol;
  const ushort_t* Wptr = W + (long)(n0 + srow) * K + swzcol;

  auto stage = [&](int buf, int step) {
    __builtin_amdgcn_global_load_lds(
        (gas_t)(const void*)(Aptr + step * 32),
        (las_t)(void*)((char*)As + buf * 8192 + soff), 16, 0, 0);
    __builtin_amdgcn_global_load_lds(
        (gas_t)(const void*)(Wptr + step * 32),
        (las_t)(void*)((char*)Bs + buf * 8192 + soff), 16, 0, 0);
  };

  f32x4 acc[4][2] = {};

  auto compute = [&](int buf) {
    const ushort_t* Ab = As + buf * (128 * 32);
    const ushort_t* Bb = Bs + buf * (128 * 32);
    bf16x8 af[4], bf[2];
#pragma unroll
    for (int t = 0; t < 4; ++t)
      af[t] = *(const bf16x8*)(Ab + (wm * 64 + t * 16 + l15) * 32 +
                               ((lgc ^ xs) << 3));
#pragma unroll
    for (int t = 0; t < 2; ++t)
      bf[t] = *(const bf16x8*)(Bb + (wn * 32 + t * 16 + l15) * 32 +
                               ((lgc ^ xs) << 3));
#pragma unroll
    for (int mt = 0; mt < 4; ++mt)
#pragma unroll
      for (int nt = 0; nt < 2; ++nt)
        acc[mt][nt] = MFMA16(af[mt], bf[nt], acc[mt][nt]);
  };

  const int NSTEP = K / 32;
  stage(0, 0);
  stage(1, 1);
  for (int s = 0; s < NSTEP - 2; ++s) {
    stage((s + 2) & 3, s + 2);
    asm volatile("s_waitcnt vmcnt(4)" ::: "memory");
    __builtin_amdgcn_s_barrier();
    __builtin_amdgcn_sched_barrier(0);
    compute(s & 3);
  }
  asm volatile("s_waitcnt vmcnt(2)" ::: "memory");
  __builtin_amdgcn_s_barrier();
  __builtin_amdgcn_sched_barrier(0);
  compute((NSTEP - 2) & 3);
  asm volatile("s_waitcnt vmcnt(0)" ::: "memory");
  __builtin_amdgcn_s_barrier();
  __builtin_amdgcn_sched_barrier(0);
  compute((NSTEP - 1) & 3);

  const int lg4 = (lane >> 4) * 4;
  ushort_t* o = outbase + (long)z * ((long)NH * L_SEQ * DH);
#pragma unroll
  for (int mt = 0; mt < 4; ++mt)
#pragma unroll
    for (int nt = 0; nt < 2; ++nt)
#pragma unroll
      for (int r = 0; r < 4; ++r) {
        int row = m0 + wm * 64 + mt * 16 + lg4 + r;
        int col = n0 + wn * 32 + nt * 16 + l15;
        float v = (acc[mt][nt][r] + bias[col]) * scale;
        o[((long)(col >> 6) * L_SEQ + row) * DH + (col & 63)] = f2b(v);
      }
}

// ---------------- out-proj GEMM: 128x64, ring-4 + T2 + T1 (R14) ----------------
__global__ __launch_bounds__(256, 3) void gemm_out(
    const ushort_t* __restrict__ A, const ushort_t* __restrict__ W,
    const float* __restrict__ bias, float* __restrict__ o) {
  const int bid = blockIdx.x;
  const int lid = (bid & 7) * 32 + (bid >> 3);
  const int m_tile = lid & 15;
  const int n_tile = lid >> 4;

  __shared__ ushort_t As[4 * 128 * 32];
  __shared__ ushort_t Bs[4 * 64 * 32];
  const int tid = threadIdx.x;
  const int lane = tid & 63;
  const int wid = tid >> 6;
  const int wm = wid >> 1, wn = wid & 1;
  const int m0 = m_tile * 128, n0 = n_tile * 64;
  const int K = D_MODEL;
  const int l15 = lane & 15;
  const int lgc = lane >> 4;
  const int xs = (l15 >> 1) & 3;

  const int soff = tid * 16;
  const int srow = soff >> 6;
  const int schunk = (soff >> 4) & 3;
  const int swzcol = ((schunk ^ ((srow >> 1) & 3)) << 3);

  const ushort_t* Aptr0 = A + (long)(m0 + srow) * K + swzcol;
  const ushort_t* Aptr1 = A + (long)(m0 + 64 + srow) * K + swzcol;
  const ushort_t* Wptr  = W + (long)(n0 + srow) * K + swzcol;

  auto stage = [&](int buf, int step) {
    __builtin_amdgcn_global_load_lds(
        (gas_t)(const void*)(Aptr0 + step * 32),
        (las_t)(void*)((char*)As + buf * 8192 + soff), 16, 0, 0);
    __builtin_amdgcn_global_load_lds(
        (gas_t)(const void*)(Aptr1 + step * 32),
        (las_t)(void*)((char*)As + buf * 8192 + 4096 + soff), 16, 0, 0);
    __builtin_amdgcn_global_load_lds(
        (gas_t)(const void*)(Wptr + step * 32),
        (las_t)(void*)((char*)Bs + buf * 4096 + soff), 16, 0, 0);
  };

  f32x4 acc[4][2] = {};

  auto compute = [&](int buf) {
    const ushort_t* Ab = As + buf * (128 * 32);
    const ushort_t* Bb = Bs + buf * (64 * 32);
    bf16x8 af[4], bf[2];
#pragma unroll
    for (int t = 0; t < 4; ++t)
      af[t] = *(const bf16x8*)(Ab + (wm * 64 + t * 16 + l15) * 32 +
                               ((lgc ^ xs) << 3));
#pragma unroll
    for (int t = 0; t < 2; ++t)
      bf[t] = *(const bf16x8*)(Bb + (wn * 32 + t * 16 + l15) * 32 +
                               ((lgc ^ xs) << 3));
#pragma unroll
    for (int mt = 0; mt < 4; ++mt)
#pragma unroll
      for (int nt = 0; nt < 2; ++nt)
        acc[mt][nt] = MFMA16(af[mt], bf[nt], acc[mt][nt]);
  };

  const int NSTEP = K / 32;
  stage(0, 0);
  stage(1, 1);
  for (int s = 0; s < NSTEP - 2; ++s) {
    stage((s + 2) & 3, s + 2);
    asm volatile("s_waitcnt vmcnt(6)" ::: "memory");
    __builtin_amdgcn_s_barrier();
    __builtin_amdgcn_sched_barrier(0);
    compute(s & 3);
  }
  asm volatile("s_waitcnt vmcnt(3)" ::: "memory");
  __builtin_amdgcn_s_barrier();
  __builtin_amdgcn_sched_barrier(0);
  compute((NSTEP - 2) & 3);
  asm volatile("s_waitcnt vmcnt(0)" ::: "memory");
  __builtin_amdgcn_s_barrier();
  __builtin_amdgcn_sched_barrier(0);
  compute((NSTEP - 1) & 3);

  const int lg4 = (lane >> 4) * 4;
#pragma unroll
  for (int mt = 0; mt < 4; ++mt)
#pragma unroll
    for (int nt = 0; nt < 2; ++nt)
#pragma unroll
      for (int r = 0; r < 4; ++r) {
        int row = m0 + wm * 64 + mt * 16 + lg4 + r;
        int col = n0 + wn * 32 + nt * 16 + l15;
        o[(long)row * D_MODEL + col] = acc[mt][nt][r] + bias[col];
      }
}

// ---------------- fused attention: 64 queries/block, 2 blocks/CU ----------------
// 1D grid 512 blocks, 256 threads (4 waves x 16 queries). XCD swizzle groups
// 2 whole heads per XCD (gathered K/V L2-resident). LDS 48.4 KB -> 2 blocks/CU
// so two independent phase-chains overlap per CU.
// K phase: kl[128][72] + kg[208][72]; V phase (aliased): vtl[64][132] + vtg[64][228].
#define VTW 228
__global__ __launch_bounds__(256) void attn_fused(
    const ushort_t* __restrict__ QKV, const int* __restrict__ gidx, int NG,
    ushort_t* __restrict__ attn_out) {
  __shared__ ushort_t smem[24192];  // 48384 B

  const int tid = threadIdx.x;
  const int lane = tid & 63;
  const int w = tid >> 6;            // 0..3
  const int bid = blockIdx.x;        // 0..511
  const int lid = (bid & 7) * 64 + (bid >> 3);
  const int h = lid >> 5;            // 0..15 (2 heads per XCD)
  const int q0 = (lid & 31) * 64;

  const long hoff = (long)h * L_SEQ * DH;
  const ushort_t* Qh = QKV + hoff;
  const ushort_t* Kh = QKV + (long)NH * L_SEQ * DH + hoff;
  const ushort_t* Vh = QKV + 2L * NH * L_SEQ * DH + hoff;

  const int l15 = lane & 15, lg = lane >> 4;
  const int ql = q0 + w * 16 + l15;

  ushort_t* kl = smem;               // 128 x 72
  ushort_t* kg = smem + 128 * 72;    // 208 x 72
  ushort_t* vtl = smem;              // 64 x 132 (V phase)
  ushort_t* vtg = smem + 64 * 132;   // 64 x 228

  // ---- issue all independent global loads first ----
  // local V: 128 rows x 8 chunks = 1024 int4, 4/thread
  int4 vstL[4];
#pragma unroll
  for (int it = 0; it < 4; ++it) {
    int c = tid + it * 256;
    int r = c >> 3, cc = (c & 7) * 8;
    int sr = q0 - 32 + r;
    sr = sr < 0 ? 0 : (sr > L_SEQ - 1 ? L_SEQ - 1 : sr);
    vstL[it] = *(const int4*)(Vh + (long)sr * DH + cc);
  }
  // global V: 1664 int4, 7/thread (last partial, clamped)
  int4 vstG[7];
#pragma unroll
  for (int it = 0; it < 7; ++it) {
    int c = tid + it * 256;
    int cl = c < 1664 ? c : 1663;
    int r = cl >> 3, cc = (cl & 7) * 8;
    int idx = r < NG ? r : NG - 1;
    vstG[it] = *(const int4*)(Vh + (long)gidx[idx] * DH + cc);
  }
  bf16x8 qf0 = *(const bf16x8*)(Qh + (long)ql * DH + lg * 8);
  bf16x8 qf1 = *(const bf16x8*)(Qh + (long)ql * DH + 32 + lg * 8);

  // ---- stage K local (1024 int4) + K global (1664 int4) ----
#pragma unroll
  for (int it = 0; it < 4; ++it) {
    int c = tid + it * 256;
    int r = c >> 3, cc = (c & 7) * 8;
    int sr = q0 - 32 + r;
    sr = sr < 0 ? 0 : (sr > L_SEQ - 1 ? L_SEQ - 1 : sr);
    int4 v = *(const int4*)(Kh + (long)sr * DH + cc);
    *(int4*)(kl + r * 72 + cc) = v;
  }
#pragma unroll
  for (int it = 0; it < 7; ++it) {
    int c = tid + it * 256;
    if (c < 1664) {
      int r = c >> 3, cc = (c & 7) * 8;
      int idx = r < NG ? r : NG - 1;
      int4 v = *(const int4*)(Kh + (long)gidx[idx] * DH + cc);
      *(int4*)(kg + r * 72 + cc) = v;
    }
  }
  __syncthreads();

  // ---- QK^T local: wave w's 5 key-tiles (rows w*16 .. w*16+80) ----
  f32x4 sl[5];
#pragma unroll
  for (int kt = 0; kt < 5; ++kt) {
    f32x4 c = {};
    const ushort_t* kr = kl + (w * 16 + kt * 16 + l15) * 72;
    bf16x8 k0 = *(const bf16x8*)(kr + lg * 8);
    bf16x8 k1 = *(const bf16x8*)(kr + 32 + lg * 8);
    c = MFMA16(k0, qf0, c);
    c = MFMA16(k1, qf1, c);
    sl[kt] = c;
  }
  // ---- QK^T global: 13 key-tiles ----
  f32x4 sg[13];
#pragma unroll
  for (int kt = 0; kt < 13; ++kt) {
    f32x4 c = {};
    bf16x8 k0 = *(const bf16x8*)(kg + (kt * 16 + l15) * 72 + lg * 8);
    bf16x8 k1 = *(const bf16x8*)(kg + (kt * 16 + l15) * 72 + 32 + lg * 8);
    c = MFMA16(k0, qf0, c);
    c = MFMA16(k1, qf1, c);
    sg[kt] = c;
  }
  __syncthreads();  // K buffers dead; smem becomes VT

  // ---- write V transposed ----
#pragma unroll
  for (int it = 0; it < 4; ++it) {
    int c = tid + it * 256;
    int r = c >> 3, cc = (c & 7) * 8;
    ushort_t tmp[8]; *(int4*)tmp = vstL[it];
#pragma unroll
    for (int j = 0; j < 8; ++j) vtl[(cc + j) * 132 + r] = tmp[j];
  }
#pragma unroll
  for (int it = 0; it < 7; ++it) {
    int c = tid + it * 256;
    if (c < 1664) {
      int r = c >> 3, cc = (c & 7) * 8;
      ushort_t tmp[8]; *(int4*)tmp = vstG[it];
#pragma unroll
      for (int j = 0; j < 8; ++j) vtg[(cc + j) * VTW + r] = tmp[j];
    }
  }
  for (int i = tid; i < 64 * 20; i += 256)
    vtg[(i / 20) * VTW + 208 + (i % 20)] = 0;

  // ---- local softmax ----
  float mx = NEG_INF;
#pragma unroll
  for (int kt = 0; kt < 5; ++kt)
#pragma unroll
    for (int r4 = 0; r4 < 4; ++r4) {
      int key = q0 - 32 + w * 16 + kt * 16 + lg * 4 + r4;
      int d = key - ql;
      bool valid = (key >= 0) && (key < L_SEQ) && (d <= 32) && (d >= -32);
      float v = valid ? sl[kt][r4] : NEG_INF;
      sl[kt][r4] = v;
      mx = fmaxf(mx, v);
    }
  mx = fmaxf(mx, __shfl_xor(mx, 16, 64));
  mx = fmaxf(mx, __shfl_xor(mx, 32, 64));
  float den = 0.f;
#pragma unroll
  for (int kt = 0; kt < 5; ++kt)
#pragma unroll
    for (int r4 = 0; r4 < 4; ++r4) {
      float e = __expf(sl[kt][r4] - mx);
      sl[kt][r4] = e;
      den += e;
    }
  den += __shfl_xor(den, 16, 64);
  den += __shfl_xor(den, 32, 64);
  const float psl = 0.7f / den;

  // ---- global softmax ----
  float mg = NEG_INF;
#pragma unroll
  for (int t = 0; t < 13; ++t)
#pragma unroll
    for (int r4 = 0; r4 < 4; ++r4) {
      int i = t * 16 + lg * 4 + r4;
      float v = (i < NG) ? sg[t][r4] : NEG_INF;
      sg[t][r4] = v;
      mg = fmaxf(mg, v);
    }
  mg = fmaxf(mg, __shfl_xor(mg, 16, 64));
  mg = fmaxf(mg, __shfl_xor(mg, 32, 64));
  float deng = 0.f;
#pragma unroll
  for (int t = 0; t < 13; ++t)
#pragma unroll
    for (int r4 = 0; r4 < 4; ++r4) {
      float e = __expf(sg[t][r4] - mg);
      sg[t][r4] = e;
      deng += e;
    }
  deng += __shfl_xor(deng, 16, 64);
  deng += __shfl_xor(deng, 32, 64);
  const float psg = 0.3f / deng;

  // ---- pack P fragments ----
  bf16x8 pl[3];
#pragma unroll
  for (int s = 0; s < 2; ++s)
#pragma unroll
    for (int j = 0; j < 4; ++j) {
      pl[s][j]     = (short)f2b(sl[2 * s][j] * psl);
      pl[s][j + 4] = (short)f2b(sl[2 * s + 1][j] * psl);
    }
#pragma unroll
  for (int j = 0; j < 4; ++j) {
    pl[2][j]     = (short)f2b(sl[4][j] * psl);
    pl[2][j + 4] = 0;
  }
  bf16x8 pg[7];
#pragma unroll
  for (int s = 0; s < 6; ++s)
#pragma unroll
    for (int j = 0; j < 4; ++j) {
      pg[s][j]     = (short)f2b(sg[2 * s][j] * psg);
      pg[s][j + 4] = (short)f2b(sg[2 * s + 1][j] * psg);
    }
#pragma unroll
  for (int j = 0; j < 4; ++j) {
    pg[6][j]     = (short)f2b(sg[12][j] * psg);
    pg[6][j + 4] = 0;
  }
  __syncthreads();  // VT ready

  // ---- PV: local (at column offset w*16) + global, ONE accumulator ----
#pragma unroll
  for (int dt = 0; dt < 4; ++dt) {
    f32x4 c = {};
    const ushort_t* vrowL = vtl + (dt * 16 + l15) * 132 + w * 16 + lg * 4;
#pragma unroll
    for (int s = 0; s < 3; ++s) {
      bf16x4 lo = *(const bf16x4*)(vrowL + s * 32);
      bf16x4 hi = *(const bf16x4*)(vrowL + s * 32 + (s < 2 ? 16 : 0));
      bf16x8 vf = __builtin_shufflevector(lo, hi, 0, 1, 2, 3, 4, 5, 6, 7);
      c = MFMA16(pl[s], vf, c);
    }
    const ushort_t* vrowG = vtg + (dt * 16 + l15) * VTW + lg * 4;
#pragma unroll
    for (int s = 0; s < 7; ++s) {
      bf16x4 lo = *(const bf16x4*)(vrowG + s * 32);
      bf16x4 hi = *(const bf16x4*)(vrowG + s * 32 + 16);
      bf16x8 vf = __builtin_shufflevector(lo, hi, 0, 1, 2, 3, 4, 5, 6, 7);
      c = MFMA16(pg[s], vf, c);
    }
#pragma unroll
    for (int r4 = 0; r4 < 4; ++r4) {
      int row = q0 + w * 16 + lg * 4 + r4;
      attn_out[(long)row * D_MODEL + h * DH + dt * 16 + l15] = f2b(c[r4]);
    }
  }
}

extern "C" void kernel_launch(void* const* d_in, const int* in_sizes, int n_in,
                              void* d_out, int out_size, void* d_ws, size_t ws_size,
                              hipStream_t stream) {
  const float* x  = (const float*)d_in[0];
  const float* Wq = (const float*)d_in[1];
  const float* bq = (const float*)d_in[2];
  const float* Wk = (const float*)d_in[3];
  const float* bk = (const float*)d_in[4];
  const float* Wv = (const float*)d_in[5];
  const float* bv = (const float*)d_in[6];
  const float* Wo = (const float*)d_in[7];
  const float* bo = (const float*)d_in[8];
  const int* gidx = (const int*)d_in[9];
  const int NG = in_sizes[9];

  ushort_t* ws = (ushort_t*)d_ws;
  ushort_t* xb    = ws;                  // x bf16: 2M elems
  ushort_t* wb    = ws + 2097152L;       // 4 weights bf16: 4 x 1M
  ushort_t* qkv   = ws + 6291456L;       // Q,K,V bf16 head-major: 3 x 2M
  ushort_t* attn  = ws + 12582912L;      // attention bf16 [L][D]: 2M

  cvt_kernel<<<6144, 256, 0, stream>>>(x, Wq, Wk, Wv, Wo, ws);
  gemm_qkv<<<384, 512, 0, stream>>>(xb, wb, bq, bk, bv, qkv);
  attn_fused<<<512, 256, 0, stream>>>(qkv, gidx, NG, attn);
  gemm_out<<<256, 256, 0, stream>>>(attn, wb + 3145728L, bo,
                                    (float*)d_out);
}